// Round 8
// baseline (196.007 us; speedup 1.0000x reference)
//
#include <hip/hip_runtime.h>

#define INV_T 14.285714285714286f  // 1/0.07
#define C1 0.055803571428571425f   // INV_T / 256 (undoes the 16x-per-input fp8 scale)

typedef float f32x16 __attribute__((ext_vector_type(16)));
typedef float f32x4 __attribute__((ext_vector_type(4)));
typedef int i32x4v __attribute__((ext_vector_type(4)));
typedef int i32x8 __attribute__((ext_vector_type(8)));

__device__ __forceinline__ unsigned char f2e4m3(float f) {
    unsigned char s = (unsigned char)((__float_as_uint(f) >> 24) & 0x80);
    float a = fabsf(f);
    if (a > 448.f) a = 448.f;
    if (a == 0.f) return s;
    int e = (int)((__float_as_uint(a) >> 23) & 0xFF) - 127;
    if (e < -10) return s;
    if (e < -6) e = -6;
    float scale = __int_as_float((unsigned)(130 - e) << 23);  // 2^(3-e)
    int mi = (int)rintf(a * scale);
    if (mi >= 16) { mi >>= 1; ++e; }
    if (mi < 8) return s | (unsigned char)mi;                  // subnormal (e==-6)
    return s | (unsigned char)(((e + 7) << 3) | (mi - 8));
}

__device__ __forceinline__ void async16(void* l, const void* g) {
    __builtin_amdgcn_global_load_lds(
        (const __attribute__((address_space(1))) unsigned int*)g,
        (__attribute__((address_space(3))) unsigned int*)l, 16, 0, 0);
}

// ---- fused prep + colsum v5: high occupancy AND atomic-free ----
// Rounds 6/7 each tested only half the fix (r6: 16 waves/CU but 1M atomics;
// r7: no atomics but 1 wave/SIMD). This is the untested quadrant:
// 1024 blocks x 8 rows (16 waves/CU) + per-block partial slices (4MB, ws is
// 268MB per r7's fillBuffer evidence). Also folds the memset dispatch in:
// each block zeroes its sumexp slice; block 0 zeroes scal/done_ctr.
__global__ void __launch_bounds__(256) k_prepcs(const float* __restrict__ emb,
                                                const float* __restrict__ center,
                                                const int* __restrict__ labels,
                                                unsigned char* __restrict__ embQ,
                                                float* __restrict__ out,
                                                float* __restrict__ Sp,
                                                float* __restrict__ s_mp,
                                                float* __restrict__ sumexp,
                                                float* __restrict__ scal,
                                                unsigned* __restrict__ done_ctr,
                                                int D) {
    int t = threadIdx.x;                 // blockDim = D/4 (=256 for D=1024)
    int wave = t >> 6, lane = t & 63;
    int nw = blockDim.x >> 6;
    int r0 = blockIdx.x * 8;

    // folded memset: zero this block's sumexp slice + global scalars
    if (t < 8) sumexp[blockIdx.x * 8 + t] = 0.f;
    if (blockIdx.x == 0) {
        if (t < 12) scal[t] = 0.f;
        if (t == 12) *done_ctr = 0u;
    }

    float4 c = ((const float4*)center)[t];

    // phase 0: issue all 8 row-loads back-to-back (ILP-8 in flight)
    float4 e[8];
#pragma unroll
    for (int r = 0; r < 8; ++r)
        e[r] = ((const float4*)(emb + (size_t)(r0 + r) * D))[t];
    int lab[8];
#pragma unroll
    for (int r = 0; r < 8; ++r) lab[r] = labels[r0 + r];

    // phase 1: fp8 convert + store
    if (embQ) {
#pragma unroll
        for (int r = 0; r < 8; ++r) {
#if __has_builtin(__builtin_amdgcn_cvt_pk_fp8_f32)
            int p = 0;
            p = __builtin_amdgcn_cvt_pk_fp8_f32(e[r].x * 16.f, e[r].y * 16.f, p, false);
            p = __builtin_amdgcn_cvt_pk_fp8_f32(e[r].z * 16.f, e[r].w * 16.f, p, true);
            ((int*)(embQ + (size_t)(r0 + r) * D))[t] = p;
#else
            ((uchar4*)(embQ + (size_t)(r0 + r) * D))[t] =
                make_uchar4(f2e4m3(e[r].x * 16.f), f2e4m3(e[r].y * 16.f),
                            f2e4m3(e[r].z * 16.f), f2e4m3(e[r].w * 16.f));
#endif
        }
    }

    // phase 2: per-row partials + column accumulation (registers only)
    float d2p[8], spp[8];
    float4 colacc = {0.f, 0.f, 0.f, 0.f};
#pragma unroll
    for (int r = 0; r < 8; ++r) {
        float sc = (lab[r] == 0) ? 1.f : 0.f;
        float dx = e[r].x - c.x, dy = e[r].y - c.y,
              dz = e[r].z - c.z, dw = e[r].w - c.w;
        d2p[r] = dx * dx + dy * dy + dz * dz + dw * dw;
        spp[r] = e[r].x * c.x + e[r].y * c.y + e[r].z * c.z + e[r].w * c.w;
        colacc.x += e[r].x * sc; colacc.y += e[r].y * sc;
        colacc.z += e[r].z * sc; colacc.w += e[r].w * sc;
    }

    // phase 3: deferred interleaved shuffle reduces (ILP=16)
#pragma unroll
    for (int m = 1; m <= 32; m <<= 1)
#pragma unroll
        for (int r = 0; r < 8; ++r) {
            d2p[r] += __shfl_xor(d2p[r], m, 64);
            spp[r] += __shfl_xor(spp[r], m, 64);
        }
    __shared__ float redD[8][4];
    __shared__ float redS[8][4];
    if (lane == 0)
#pragma unroll
        for (int r = 0; r < 8; ++r) { redD[r][wave] = d2p[r]; redS[r][wave] = spp[r]; }

    // private partial slice: coalesced store, NO atomics
    ((float4*)(s_mp + (size_t)blockIdx.x * D))[t] = colacc;

    __syncthreads();
    if (t < 8) {
        float d2 = 0.f, sp = 0.f;
        for (int w = 0; w < nw; ++w) { d2 += redD[t][w]; sp += redS[t][w]; }
        out[5 + r0 + t] = sqrtf(d2);
        Sp[r0 + t] = sp * INV_T;
    }
}

// ---- sumexp via MX fp8 MFMA (round-0 best structure + XCD swizzle) ----
#define MXMFMA(a, b, c) __builtin_amdgcn_mfma_scale_f32_32x32x64_f8f6f4( \
    (a), (b), (c), 0, 0, 0, 0x7F7F7F7F, 0, 0x7F7F7F7F)

__global__ void __launch_bounds__(256, 2)
k_sumexp_mx(const unsigned char* __restrict__ embQ, float* __restrict__ sumexp,
            int D, int nT) {
    const int n = nT;
    int nwg = n * (n + 1) / 2;
    int bid = blockIdx.x;
    if ((nwg & 7) == 0) {                 // XCD-aware swizzle (bijective: nwg%8==0)
        int cpx = nwg >> 3;
        bid = (bid & 7) * cpx + (bid >> 3);
    }
    float nf = (float)n + 0.5f;
    int rb = (int)(nf - sqrtf(fmaxf(nf * nf - 2.0f * (float)bid, 0.f)));
    if (rb < 0) rb = 0;
    if (rb > n - 1) rb = n - 1;
#define TRI_OFF(r) ((r) * n - ((r) * ((r)-1)) / 2)
    while (rb + 1 <= n - 1 && TRI_OFF(rb + 1) <= bid) ++rb;
    while (rb > 0 && TRI_OFF(rb) > bid) --rb;
    int cb = rb + (bid - TRI_OFF(rb));
#undef TRI_OFF
    int rowbase = rb * 128, colbase = cb * 128;

    int tid = threadIdx.x;
    int wave = tid >> 6, lane = tid & 63;
    int wr = wave >> 1, wc = wave & 1;
    int l31 = lane & 31, kk = lane >> 5;

    __shared__ unsigned char sA[2][16384];
    __shared__ unsigned char sB[2][16384];
    __shared__ float rred[2][128];
    __shared__ float cred[2][128];

    f32x16 acc[2][2];
#pragma unroll
    for (int fr = 0; fr < 2; ++fr)
#pragma unroll
        for (int fc = 0; fc < 2; ++fc)
#pragma unroll
            for (int v = 0; v < 16; ++v) acc[fr][fc][v] = 0.f;

    const int kG = D >> 7;

    const unsigned char* gSA[4];
    const unsigned char* gSB[4];
    unsigned int dstOff[4];
#pragma unroll
    for (int q = 0; q < 4; ++q) {
        int ch = q * 256 + tid;
        int row = ch >> 3, lc = ch & 7;
        int gc = lc ^ (row & 7);
        gSA[q] = embQ + (size_t)(rowbase + row) * D + gc * 16;
        gSB[q] = embQ + (size_t)(colbase + row) * D + gc * 16;
        dstOff[q] = (unsigned)ch << 4;
    }

    auto stage = [&](int buf, int kt) {
        int ko = kt << 7;
#pragma unroll
        for (int q = 0; q < 4; ++q) {
            async16(&sA[buf][dstOff[q]], gSA[q] + ko);
            async16(&sB[buf][dstOff[q]], gSB[q] + ko);
        }
    };

    int e7 = (l31 & 7) << 4;
    int offs[2][2];
#pragma unroll
    for (int h = 0; h < 2; ++h)
#pragma unroll
        for (int j = 0; j < 2; ++j)
            offs[h][j] = (((h * 4 + kk * 2 + j) << 4) ^ e7);
    int aBase0 = (wr * 64 + l31) << 7;
    int aBase1 = aBase0 + (32 << 7);
    int bBase0 = (wc * 64 + l31) << 7;
    int bBase1 = bBase0 + (32 << 7);

    stage(0, 0);
    for (int kt = 0; kt < kG; ++kt) {
        int cur = kt & 1;
        __syncthreads();
        if (kt + 1 < kG) stage(cur ^ 1, kt + 1);
        const unsigned char* A = sA[cur];
        const unsigned char* Bp = sB[cur];
#pragma unroll
        for (int h = 0; h < 2; ++h) {
            i32x8 av[2], bv[2];
            {
                i32x4v lo = *(const i32x4v*)&A[aBase0 + offs[h][0]];
                i32x4v hi = *(const i32x4v*)&A[aBase0 + offs[h][1]];
                av[0] = __builtin_shufflevector(lo, hi, 0, 1, 2, 3, 4, 5, 6, 7);
            }
            {
                i32x4v lo = *(const i32x4v*)&A[aBase1 + offs[h][0]];
                i32x4v hi = *(const i32x4v*)&A[aBase1 + offs[h][1]];
                av[1] = __builtin_shufflevector(lo, hi, 0, 1, 2, 3, 4, 5, 6, 7);
            }
            {
                i32x4v lo = *(const i32x4v*)&Bp[bBase0 + offs[h][0]];
                i32x4v hi = *(const i32x4v*)&Bp[bBase0 + offs[h][1]];
                bv[0] = __builtin_shufflevector(lo, hi, 0, 1, 2, 3, 4, 5, 6, 7);
            }
            {
                i32x4v lo = *(const i32x4v*)&Bp[bBase1 + offs[h][0]];
                i32x4v hi = *(const i32x4v*)&Bp[bBase1 + offs[h][1]];
                bv[1] = __builtin_shufflevector(lo, hi, 0, 1, 2, 3, 4, 5, 6, 7);
            }
#pragma unroll
            for (int fr = 0; fr < 2; ++fr)
#pragma unroll
                for (int fc = 0; fc < 2; ++fc)
                    acc[fr][fc] = MXMFMA(av[fr], bv[fc], acc[fr][fc]);
        }
    }

    float rs[2][16];
    float cs[2] = {0.f, 0.f};
#pragma unroll
    for (int fr = 0; fr < 2; ++fr)
#pragma unroll
        for (int v = 0; v < 16; ++v) rs[fr][v] = 0.f;

#pragma unroll
    for (int fr = 0; fr < 2; ++fr)
#pragma unroll
        for (int fc = 0; fc < 2; ++fc) {
            int gcol = colbase + wc * 64 + fc * 32 + l31;
#pragma unroll
            for (int v = 0; v < 16; ++v) {
                int grow = rowbase + wr * 64 + fr * 32 + (v & 3) + 8 * (v >> 2) + 4 * kk;
                float e = (grow < gcol) ? __expf(acc[fr][fc][v] * C1 - INV_T) : 0.f;
                rs[fr][v] += e;
                cs[fc] += e;
            }
        }

#pragma unroll
    for (int m = 1; m <= 16; m <<= 1)
#pragma unroll
        for (int fr = 0; fr < 2; ++fr)
#pragma unroll
            for (int v = 0; v < 16; ++v) rs[fr][v] += __shfl_xor(rs[fr][v], m, 64);
    if (l31 == 0)
#pragma unroll
        for (int fr = 0; fr < 2; ++fr)
#pragma unroll
            for (int v = 0; v < 16; ++v)
                rred[wc][wr * 64 + fr * 32 + (v & 3) + 8 * (v >> 2) + 4 * kk] = rs[fr][v];

#pragma unroll
    for (int fc = 0; fc < 2; ++fc) cs[fc] += __shfl_xor(cs[fc], 32, 64);
    if (kk == 0)
#pragma unroll
        for (int fc = 0; fc < 2; ++fc) cred[wr][wc * 64 + fc * 32 + l31] = cs[fc];

    __syncthreads();
    if (tid < 128) {
        atomicAdd(&sumexp[rowbase + tid], rred[0][tid] + rred[1][tid]);
    } else {
        int u = tid - 128;
        atomicAdd(&sumexp[colbase + u], cred[0][u] + cred[1][u]);
    }
}

// ---- fallback (no workspace): bf16-via-LDS, fp32 inline convert ----
typedef __bf16 bf16x8 __attribute__((ext_vector_type(8)));
typedef unsigned short u16x8 __attribute__((ext_vector_type(8)));
__device__ __forceinline__ unsigned short f2bf(float f) {
    unsigned int x = __float_as_uint(f);
    x += 0x7fffu + ((x >> 16) & 1u);
    return (unsigned short)(x >> 16);
}
__global__ void __launch_bounds__(256) k_sumexp_fb(const float* __restrict__ embF,
                                                   float* __restrict__ sumexp, int D, int nTiles) {
    int bid = blockIdx.x;
    const int n = nTiles;
    float nf = (float)n + 0.5f;
    int rb = (int)(nf - sqrtf(fmaxf(nf * nf - 2.0f * (float)bid, 0.f)));
    if (rb < 0) rb = 0;
    if (rb > n - 1) rb = n - 1;
#define TRI_OFF(r) ((r) * n - ((r) * ((r)-1)) / 2)
    while (rb + 1 <= n - 1 && TRI_OFF(rb + 1) <= bid) ++rb;
    while (rb > 0 && TRI_OFF(rb) > bid) --rb;
    int cb = rb + (bid - TRI_OFF(rb));
#undef TRI_OFF
    int tid = threadIdx.x;
    int wave = tid >> 6, lane = tid & 63;
    int wr = wave >> 1, wc = wave & 1;
    int quad = lane >> 4, l15 = lane & 15;
    int rowbase = rb * 128, colbase = cb * 128;
    __shared__ unsigned short lA[128 * 64];
    __shared__ unsigned short lB[128 * 64];
    __shared__ float rred[2][128];
    __shared__ float cred[2][128];
    f32x4 zero = {0.f, 0.f, 0.f, 0.f};
    f32x4 acc[4][4];
#pragma unroll
    for (int r = 0; r < 4; ++r)
#pragma unroll
        for (int c = 0; c < 4; ++c) acc[r][c] = zero;
    const int kIters = D >> 6;
    for (int kt = 0; kt < kIters; ++kt) {
        int k0 = kt << 6;
#pragma unroll
        for (int q = 0; q < 4; ++q) {
            int ch = q * 256 + tid;
            int row = ch >> 3, lc = ch & 7;
            int pc = lc ^ (row & 7);
            const float4* sa = (const float4*)(embF + (size_t)(rowbase + row) * D + k0 + lc * 8);
            const float4* sb = (const float4*)(embF + (size_t)(colbase + row) * D + k0 + lc * 8);
            float4 a0 = sa[0], a1 = sa[1];
            float4 b0 = sb[0], b1 = sb[1];
            u16x8 va = {f2bf(a0.x), f2bf(a0.y), f2bf(a0.z), f2bf(a0.w),
                        f2bf(a1.x), f2bf(a1.y), f2bf(a1.z), f2bf(a1.w)};
            u16x8 vb = {f2bf(b0.x), f2bf(b0.y), f2bf(b0.z), f2bf(b0.w),
                        f2bf(b1.x), f2bf(b1.y), f2bf(b1.z), f2bf(b1.w)};
            *(u16x8*)&lA[(row << 6) + (pc << 3)] = va;
            *(u16x8*)&lB[(row << 6) + (pc << 3)] = vb;
        }
        __syncthreads();
#pragma unroll
        for (int h = 0; h < 2; ++h) {
            bf16x8 af[4], bfr[4];
#pragma unroll
            for (int r = 0; r < 4; ++r) {
                int row = wr * 64 + r * 16 + l15;
                int pc = (h * 4 + quad) ^ (l15 & 7);
                af[r] = *(const bf16x8*)&lA[(row << 6) + (pc << 3)];
            }
#pragma unroll
            for (int c = 0; c < 4; ++c) {
                int row = wc * 64 + c * 16 + l15;
                int pc = (h * 4 + quad) ^ (l15 & 7);
                bfr[c] = *(const bf16x8*)&lB[(row << 6) + (pc << 3)];
            }
#pragma unroll
            for (int r = 0; r < 4; ++r)
#pragma unroll
                for (int c = 0; c < 4; ++c)
                    acc[r][c] = __builtin_amdgcn_mfma_f32_16x16x32_bf16(af[r], bfr[c], acc[r][c], 0, 0, 0);
        }
        __syncthreads();
    }
    float rs[4][4], cs[4];
#pragma unroll
    for (int r = 0; r < 4; ++r)
#pragma unroll
        for (int v = 0; v < 4; ++v) rs[r][v] = 0.f;
#pragma unroll
    for (int c = 0; c < 4; ++c) cs[c] = 0.f;
#pragma unroll
    for (int r = 0; r < 4; ++r)
#pragma unroll
        for (int c = 0; c < 4; ++c) {
            f32x4 a = acc[r][c];
            int gcol = colbase + wc * 64 + c * 16 + l15;
#pragma unroll
            for (int v = 0; v < 4; ++v) {
                int grow = rowbase + wr * 64 + r * 16 + quad * 4 + v;
                float e = (grow < gcol) ? __expf((a[v] - 1.0f) * INV_T) : 0.f;
                rs[r][v] += e;
                cs[c] += e;
            }
        }
#pragma unroll
    for (int m = 1; m <= 8; m <<= 1)
#pragma unroll
        for (int r = 0; r < 4; ++r)
#pragma unroll
            for (int v = 0; v < 4; ++v) rs[r][v] += __shfl_xor(rs[r][v], m, 64);
    if (l15 == 0)
#pragma unroll
        for (int r = 0; r < 4; ++r)
#pragma unroll
            for (int v = 0; v < 4; ++v)
                rred[wc][wr * 64 + r * 16 + quad * 4 + v] = rs[r][v];
#pragma unroll
    for (int m = 16; m <= 32; m <<= 1)
#pragma unroll
        for (int c = 0; c < 4; ++c) cs[c] += __shfl_xor(cs[c], m, 64);
    if (quad == 0)
#pragma unroll
        for (int c = 0; c < 4; ++c) cred[wr][wc * 64 + c * 16 + l15] = cs[c];
    __syncthreads();
    if (tid < 128) {
        atomicAdd(&sumexp[rowbase + tid], rred[0][tid] + rred[1][tid]);
    } else {
        int u = tid & 127;
        atomicAdd(&sumexp[colbase + u], cred[0][u] + cred[1][u]);
    }
}

// ---- finalize, emb-free + parallel s_mp reduction + folded combine ----
// sum_m q = ||s_m||^2, s_m = sum of nPart partial slices. Machine count
// folded into the per-row pass (a[8]) -> no pre-zeroed cnt needed.
__global__ void __launch_bounds__(256) k_fin(const float* __restrict__ Sp,
                                             const float* __restrict__ sumexp,
                                             const int* __restrict__ labels,
                                             const float* __restrict__ outv,
                                             const float* __restrict__ s_mp,
                                             const float* __restrict__ center,
                                             const float* __restrict__ rmp,
                                             const float* __restrict__ rhp,
                                             float* __restrict__ scal,
                                             unsigned* __restrict__ done_ctr,
                                             float* __restrict__ out,
                                             int D, int B, int nPart) {
    int t = threadIdx.x, lane = t & 63, wave = t >> 6;
    int i = blockIdx.x * blockDim.x + t;
    float rm = rmp[0], rh = rhp[0];
    float a[9];
#pragma unroll
    for (int k = 0; k < 9; ++k) a[k] = 0.f;
    if (i < B) {
        float LP = Sp[i];
        float eS = __expf(LP - INV_T);
        float lse = INV_T + __logf(sumexp[i] + eS);
        float d = outv[5 + i];
        bool mach = (labels[i] == 0);
        a[2] = eS;
        if (mach) {
            a[4] = lse; a[3] = LP; a[5] = d * d; a[8] = 1.f;
            float x = d - rm; a[0] = (x > 0.f) ? x * x : 0.f;
        } else {
            float x = rh - d; a[1] = (x > 0.f) ? x * x : 0.f;
        }
    }
    // ||c||^2: block 0
    if (blockIdx.x == 0)
        for (int j = t; j < D; j += blockDim.x) { float cv = center[j]; a[7] += cv * cv; }
    // s_mp reduction: dims partitioned across ALL blocks; 8 partial-groups/dim
    __shared__ float sacc[8][33];
    int pg = t >> 5, dl = t & 31;
    for (int dbase = blockIdx.x * 32; dbase < D; dbase += gridDim.x * 32) {
        int d = dbase + dl;
        float accp = 0.f;
        if (d < D)
            for (int p = pg; p < nPart; p += 8) accp += s_mp[(size_t)p * D + d];
        sacc[pg][dl] = accp;
        __syncthreads();
        if (t < 32 && dbase + t < D) {
            float s = sacc[0][t] + sacc[1][t] + sacc[2][t] + sacc[3][t] +
                      sacc[4][t] + sacc[5][t] + sacc[6][t] + sacc[7][t];
            a[6] += s * s;
        }
        __syncthreads();
    }
#pragma unroll
    for (int m = 1; m <= 32; m <<= 1)
#pragma unroll
        for (int k = 0; k < 9; ++k) a[k] += __shfl_xor(a[k], m, 64);
    __shared__ float red[4][9];
    if (lane == 0)
#pragma unroll
        for (int k = 0; k < 9; ++k) red[wave][k] = a[k];
    __syncthreads();
    if (t < 9) {
        float v = red[0][t] + red[1][t] + red[2][t] + red[3][t];
        atomicAdd(&scal[t], v);
    }
    __syncthreads();
    if (t == 0) {
        __threadfence();
        unsigned done = atomicAdd(done_ctr, 1u);
        if (done == (unsigned)gridDim.x - 1) {
            __threadfence();
            float s[9];
#pragma unroll
            for (int k = 0; k < 9; ++k) s[k] = atomicAdd(&scal[k], 0.f);
            int nm = (int)(s[8] + 0.5f);
            int nh = B - nm;
            float nmf = (float)(nm > 1 ? nm : 1);
            float nhf = (float)(nh > 1 ? nh : 1);
            float loss_m = s[0] / nmf;
            float loss_h = s[1] / nhf;
            float loss_shell = loss_m + loss_h;
            float lse_p = INV_T + __logf(s[2]);
            float proto = lse_p - s[3] / nmf;
            // sum_m sd = sum_m d^2 + (2/INV_T) * sum_m LP - nm * ||c||^2
            float sum_sd = s[5] + 2.f * s[3] / INV_T - (float)nm * s[7];
            float pos_m = INV_T * (s[6] - sum_sd) + s[3];
            float con = s[4] - pos_m / nmf;
            int denom = (nm + 1 > 1) ? nm + 1 : 1;
            float lc = (con + proto) / (float)denom;
            if (!(nm > 0 && nh > 0)) lc = 0.f;
            out[0] = loss_shell + lc;
            out[1] = loss_shell;
            out[2] = loss_m;
            out[3] = loss_h;
            out[4] = lc;
        }
    }
}

extern "C" void kernel_launch(void* const* d_in, const int* in_sizes, int n_in,
                              void* d_out, int out_size, void* d_ws, size_t ws_size,
                              hipStream_t stream) {
    const float* emb = (const float*)d_in[0];
    const float* center = (const float*)d_in[1];
    const float* rmp = (const float*)d_in[2];
    const float* rhp = (const float*)d_in[3];
    const int* labels = (const int*)d_in[4];
    float* out = (float*)d_out;
    const int B = in_sizes[4];
    const int D = in_sizes[1];

    const int nPart = B / 8;             // prepcs blocks = partial slices
    size_t qBytes = (size_t)B * D;       // fp8 copy
    size_t partBytes = (size_t)nPart * D * 4;
    size_t auxBytes = (size_t)B * 4 + (size_t)B * 4 + 64 + partBytes;
    bool pre = (ws_size >= qBytes + auxBytes) && (B % 128 == 0) &&
               (D % 128 == 0) && (D <= 1024);
    size_t Z0 = pre ? qBytes : 0;

    char* ws = (char*)d_ws;
    unsigned char* embQ = (unsigned char*)ws;
    float* sumexp = (float*)(ws + Z0);                        // B*4 (zeroed by prepcs)
    float* Sp = (float*)(ws + Z0 + (size_t)B * 4);            // B*4 (fully written)
    float* scal = (float*)(ws + Z0 + (size_t)B * 8);          // 64B (zeroed by prepcs)
    unsigned* done_ctr = (unsigned*)(scal + 12);
    float* s_mp = (float*)(ws + Z0 + (size_t)B * 8 + 64);     // partials (fully written)

    // 3 dispatches total; no memset (prepcs zeroes sumexp/scal/done_ctr)
    k_prepcs<<<B / 8, D / 4, 0, stream>>>(emb, center, labels,
                                          pre ? embQ : nullptr, out, Sp, s_mp,
                                          sumexp, scal, done_ctr, D);

    int nT = B / 128;
    int nBlocks = nT * (nT + 1) / 2;
    if (pre) k_sumexp_mx<<<nBlocks, 256, 0, stream>>>(embQ, sumexp, D, nT);
    else     k_sumexp_fb<<<nBlocks, 256, 0, stream>>>(emb, sumexp, D, nT);

    k_fin<<<(B + 255) / 256, 256, 0, stream>>>(Sp, sumexp, labels, out, s_mp,
                                               center, rmp, rhp, scal,
                                               done_ctr, out, D, B, nPart);
}

// Round 9
// 172.628 us; speedup vs baseline: 1.1354x; 1.1354x over previous
//
#include <hip/hip_runtime.h>

#define INV_T 14.285714285714286f  // 1/0.07
#define C1 0.055803571428571425f   // INV_T / 256 (undoes the 16x-per-input fp8 scale)

typedef float f32x16 __attribute__((ext_vector_type(16)));
typedef float f32x4 __attribute__((ext_vector_type(4)));
typedef int i32x4v __attribute__((ext_vector_type(4)));
typedef int i32x8 __attribute__((ext_vector_type(8)));

__device__ __forceinline__ unsigned char f2e4m3(float f) {
    unsigned char s = (unsigned char)((__float_as_uint(f) >> 24) & 0x80);
    float a = fabsf(f);
    if (a > 448.f) a = 448.f;
    if (a == 0.f) return s;
    int e = (int)((__float_as_uint(a) >> 23) & 0xFF) - 127;
    if (e < -10) return s;
    if (e < -6) e = -6;
    float scale = __int_as_float((unsigned)(130 - e) << 23);  // 2^(3-e)
    int mi = (int)rintf(a * scale);
    if (mi >= 16) { mi >>= 1; ++e; }
    if (mi < 8) return s | (unsigned char)mi;                  // subnormal (e==-6)
    return s | (unsigned char)(((e + 7) << 3) | (mi - 8));
}

__device__ __forceinline__ void async16(void* l, const void* g) {
    __builtin_amdgcn_global_load_lds(
        (const __attribute__((address_space(1))) unsigned int*)g,
        (__attribute__((address_space(3))) unsigned int*)l, 16, 0, 0);
}

// ---- ABLATION SPLIT of r8's prepcs: k_quant + k_geom (union == r8 body) ----
// Rounds 5-8: ILP, occupancy, atomics all nulled; prepcs invariant ~65-90us
// vs ~7us roofline. Splitting forces per-phase counters into the profile.
// A structural cost follows its phase; a first-kernel (DVFS/L2-poison) tax
// stays with whoever runs first (k_quant).

// Phase A: pure fp8 recode stream (+ folded zeroing). 1024 blocks x 8 rows.
__global__ void __launch_bounds__(256) k_quant(const float* __restrict__ emb,
                                               unsigned char* __restrict__ embQ,
                                               float* __restrict__ sumexp,
                                               float* __restrict__ scal,
                                               unsigned* __restrict__ done_ctr,
                                               int D) {
    int t = threadIdx.x;                 // blockDim = D/4
    int r0 = blockIdx.x * 8;
    if (t < 8) sumexp[blockIdx.x * 8 + t] = 0.f;
    if (blockIdx.x == 0) {
        if (t < 12) scal[t] = 0.f;
        if (t == 12) *done_ctr = 0u;
    }
    float4 e[8];
#pragma unroll
    for (int r = 0; r < 8; ++r)
        e[r] = ((const float4*)(emb + (size_t)(r0 + r) * D))[t];
#pragma unroll
    for (int r = 0; r < 8; ++r) {
#if __has_builtin(__builtin_amdgcn_cvt_pk_fp8_f32)
        int p = 0;
        p = __builtin_amdgcn_cvt_pk_fp8_f32(e[r].x * 16.f, e[r].y * 16.f, p, false);
        p = __builtin_amdgcn_cvt_pk_fp8_f32(e[r].z * 16.f, e[r].w * 16.f, p, true);
        ((int*)(embQ + (size_t)(r0 + r) * D))[t] = p;
#else
        ((uchar4*)(embQ + (size_t)(r0 + r) * D))[t] =
            make_uchar4(f2e4m3(e[r].x * 16.f), f2e4m3(e[r].y * 16.f),
                        f2e4m3(e[r].z * 16.f), f2e4m3(e[r].w * 16.f));
#endif
    }
}

// Phase B: geometry (distance/Sp) + machine column partials. 512 blocks x 16.
__global__ void __launch_bounds__(256) k_geom(const float* __restrict__ emb,
                                              const float* __restrict__ center,
                                              const int* __restrict__ labels,
                                              float* __restrict__ out,
                                              float* __restrict__ Sp,
                                              float* __restrict__ s_mp,
                                              int D) {
    int t = threadIdx.x;                 // blockDim = D/4
    int wave = t >> 6, lane = t & 63;
    int nw = blockDim.x >> 6;
    int r0 = blockIdx.x * 16;
    float4 c = ((const float4*)center)[t];
    float d2p[16], spp[16];
    float4 colacc = {0.f, 0.f, 0.f, 0.f};
#pragma unroll
    for (int g = 0; g < 2; ++g) {
        int rbase = r0 + g * 8;
        float4 e[8];
#pragma unroll
        for (int r = 0; r < 8; ++r)
            e[r] = ((const float4*)(emb + (size_t)(rbase + r) * D))[t];
        int lab[8];
#pragma unroll
        for (int r = 0; r < 8; ++r) lab[r] = labels[rbase + r];
#pragma unroll
        for (int r = 0; r < 8; ++r) {
            float sc = (lab[r] == 0) ? 1.f : 0.f;
            float dx = e[r].x - c.x, dy = e[r].y - c.y,
                  dz = e[r].z - c.z, dw = e[r].w - c.w;
            d2p[g * 8 + r] = dx * dx + dy * dy + dz * dz + dw * dw;
            spp[g * 8 + r] = e[r].x * c.x + e[r].y * c.y + e[r].z * c.z + e[r].w * c.w;
            colacc.x += e[r].x * sc; colacc.y += e[r].y * sc;
            colacc.z += e[r].z * sc; colacc.w += e[r].w * sc;
        }
    }
    // deferred interleaved shuffle reduces (32 independent chains)
#pragma unroll
    for (int m = 1; m <= 32; m <<= 1)
#pragma unroll
        for (int r = 0; r < 16; ++r) {
            d2p[r] += __shfl_xor(d2p[r], m, 64);
            spp[r] += __shfl_xor(spp[r], m, 64);
        }
    __shared__ float redD[16][4];
    __shared__ float redS[16][4];
    if (lane == 0)
#pragma unroll
        for (int r = 0; r < 16; ++r) { redD[r][wave] = d2p[r]; redS[r][wave] = spp[r]; }

    ((float4*)(s_mp + (size_t)blockIdx.x * D))[t] = colacc;  // slice, no atomics

    __syncthreads();
    if (t < 16) {
        float d2 = 0.f, sp = 0.f;
        for (int w = 0; w < nw; ++w) { d2 += redD[t][w]; sp += redS[t][w]; }
        out[5 + r0 + t] = sqrtf(d2);
        Sp[r0 + t] = sp * INV_T;
    }
}

// ---- sumexp via MX fp8 MFMA (round-0 best structure + XCD swizzle) ----
#define MXMFMA(a, b, c) __builtin_amdgcn_mfma_scale_f32_32x32x64_f8f6f4( \
    (a), (b), (c), 0, 0, 0, 0x7F7F7F7F, 0, 0x7F7F7F7F)

__global__ void __launch_bounds__(256, 2)
k_sumexp_mx(const unsigned char* __restrict__ embQ, float* __restrict__ sumexp,
            int D, int nT) {
    const int n = nT;
    int nwg = n * (n + 1) / 2;
    int bid = blockIdx.x;
    if ((nwg & 7) == 0) {                 // XCD-aware swizzle (bijective: nwg%8==0)
        int cpx = nwg >> 3;
        bid = (bid & 7) * cpx + (bid >> 3);
    }
    float nf = (float)n + 0.5f;
    int rb = (int)(nf - sqrtf(fmaxf(nf * nf - 2.0f * (float)bid, 0.f)));
    if (rb < 0) rb = 0;
    if (rb > n - 1) rb = n - 1;
#define TRI_OFF(r) ((r) * n - ((r) * ((r)-1)) / 2)
    while (rb + 1 <= n - 1 && TRI_OFF(rb + 1) <= bid) ++rb;
    while (rb > 0 && TRI_OFF(rb) > bid) --rb;
    int cb = rb + (bid - TRI_OFF(rb));
#undef TRI_OFF
    int rowbase = rb * 128, colbase = cb * 128;

    int tid = threadIdx.x;
    int wave = tid >> 6, lane = tid & 63;
    int wr = wave >> 1, wc = wave & 1;
    int l31 = lane & 31, kk = lane >> 5;

    __shared__ unsigned char sA[2][16384];
    __shared__ unsigned char sB[2][16384];
    __shared__ float rred[2][128];
    __shared__ float cred[2][128];

    f32x16 acc[2][2];
#pragma unroll
    for (int fr = 0; fr < 2; ++fr)
#pragma unroll
        for (int fc = 0; fc < 2; ++fc)
#pragma unroll
            for (int v = 0; v < 16; ++v) acc[fr][fc][v] = 0.f;

    const int kG = D >> 7;

    const unsigned char* gSA[4];
    const unsigned char* gSB[4];
    unsigned int dstOff[4];
#pragma unroll
    for (int q = 0; q < 4; ++q) {
        int ch = q * 256 + tid;
        int row = ch >> 3, lc = ch & 7;
        int gc = lc ^ (row & 7);
        gSA[q] = embQ + (size_t)(rowbase + row) * D + gc * 16;
        gSB[q] = embQ + (size_t)(colbase + row) * D + gc * 16;
        dstOff[q] = (unsigned)ch << 4;
    }

    auto stage = [&](int buf, int kt) {
        int ko = kt << 7;
#pragma unroll
        for (int q = 0; q < 4; ++q) {
            async16(&sA[buf][dstOff[q]], gSA[q] + ko);
            async16(&sB[buf][dstOff[q]], gSB[q] + ko);
        }
    };

    int e7 = (l31 & 7) << 4;
    int offs[2][2];
#pragma unroll
    for (int h = 0; h < 2; ++h)
#pragma unroll
        for (int j = 0; j < 2; ++j)
            offs[h][j] = (((h * 4 + kk * 2 + j) << 4) ^ e7);
    int aBase0 = (wr * 64 + l31) << 7;
    int aBase1 = aBase0 + (32 << 7);
    int bBase0 = (wc * 64 + l31) << 7;
    int bBase1 = bBase0 + (32 << 7);

    stage(0, 0);
    for (int kt = 0; kt < kG; ++kt) {
        int cur = kt & 1;
        __syncthreads();
        if (kt + 1 < kG) stage(cur ^ 1, kt + 1);
        const unsigned char* A = sA[cur];
        const unsigned char* Bp = sB[cur];
#pragma unroll
        for (int h = 0; h < 2; ++h) {
            i32x8 av[2], bv[2];
            {
                i32x4v lo = *(const i32x4v*)&A[aBase0 + offs[h][0]];
                i32x4v hi = *(const i32x4v*)&A[aBase0 + offs[h][1]];
                av[0] = __builtin_shufflevector(lo, hi, 0, 1, 2, 3, 4, 5, 6, 7);
            }
            {
                i32x4v lo = *(const i32x4v*)&A[aBase1 + offs[h][0]];
                i32x4v hi = *(const i32x4v*)&A[aBase1 + offs[h][1]];
                av[1] = __builtin_shufflevector(lo, hi, 0, 1, 2, 3, 4, 5, 6, 7);
            }
            {
                i32x4v lo = *(const i32x4v*)&Bp[bBase0 + offs[h][0]];
                i32x4v hi = *(const i32x4v*)&Bp[bBase0 + offs[h][1]];
                bv[0] = __builtin_shufflevector(lo, hi, 0, 1, 2, 3, 4, 5, 6, 7);
            }
            {
                i32x4v lo = *(const i32x4v*)&Bp[bBase1 + offs[h][0]];
                i32x4v hi = *(const i32x4v*)&Bp[bBase1 + offs[h][1]];
                bv[1] = __builtin_shufflevector(lo, hi, 0, 1, 2, 3, 4, 5, 6, 7);
            }
#pragma unroll
            for (int fr = 0; fr < 2; ++fr)
#pragma unroll
                for (int fc = 0; fc < 2; ++fc)
                    acc[fr][fc] = MXMFMA(av[fr], bv[fc], acc[fr][fc]);
        }
    }

    float rs[2][16];
    float cs[2] = {0.f, 0.f};
#pragma unroll
    for (int fr = 0; fr < 2; ++fr)
#pragma unroll
        for (int v = 0; v < 16; ++v) rs[fr][v] = 0.f;

#pragma unroll
    for (int fr = 0; fr < 2; ++fr)
#pragma unroll
        for (int fc = 0; fc < 2; ++fc) {
            int gcol = colbase + wc * 64 + fc * 32 + l31;
#pragma unroll
            for (int v = 0; v < 16; ++v) {
                int grow = rowbase + wr * 64 + fr * 32 + (v & 3) + 8 * (v >> 2) + 4 * kk;
                float e = (grow < gcol) ? __expf(acc[fr][fc][v] * C1 - INV_T) : 0.f;
                rs[fr][v] += e;
                cs[fc] += e;
            }
        }

#pragma unroll
    for (int m = 1; m <= 16; m <<= 1)
#pragma unroll
        for (int fr = 0; fr < 2; ++fr)
#pragma unroll
            for (int v = 0; v < 16; ++v) rs[fr][v] += __shfl_xor(rs[fr][v], m, 64);
    if (l31 == 0)
#pragma unroll
        for (int fr = 0; fr < 2; ++fr)
#pragma unroll
            for (int v = 0; v < 16; ++v)
                rred[wc][wr * 64 + fr * 32 + (v & 3) + 8 * (v >> 2) + 4 * kk] = rs[fr][v];

#pragma unroll
    for (int fc = 0; fc < 2; ++fc) cs[fc] += __shfl_xor(cs[fc], 32, 64);
    if (kk == 0)
#pragma unroll
        for (int fc = 0; fc < 2; ++fc) cred[wr][wc * 64 + fc * 32 + l31] = cs[fc];

    __syncthreads();
    if (tid < 128) {
        atomicAdd(&sumexp[rowbase + tid], rred[0][tid] + rred[1][tid]);
    } else {
        int u = tid - 128;
        atomicAdd(&sumexp[colbase + u], cred[0][u] + cred[1][u]);
    }
}

// ---- fallback (no workspace): bf16-via-LDS, fp32 inline convert ----
typedef __bf16 bf16x8 __attribute__((ext_vector_type(8)));
typedef unsigned short u16x8 __attribute__((ext_vector_type(8)));
__device__ __forceinline__ unsigned short f2bf(float f) {
    unsigned int x = __float_as_uint(f);
    x += 0x7fffu + ((x >> 16) & 1u);
    return (unsigned short)(x >> 16);
}
__global__ void __launch_bounds__(256) k_sumexp_fb(const float* __restrict__ embF,
                                                   float* __restrict__ sumexp, int D, int nTiles) {
    int bid = blockIdx.x;
    const int n = nTiles;
    float nf = (float)n + 0.5f;
    int rb = (int)(nf - sqrtf(fmaxf(nf * nf - 2.0f * (float)bid, 0.f)));
    if (rb < 0) rb = 0;
    if (rb > n - 1) rb = n - 1;
#define TRI_OFF(r) ((r) * n - ((r) * ((r)-1)) / 2)
    while (rb + 1 <= n - 1 && TRI_OFF(rb + 1) <= bid) ++rb;
    while (rb > 0 && TRI_OFF(rb) > bid) --rb;
    int cb = rb + (bid - TRI_OFF(rb));
#undef TRI_OFF
    int tid = threadIdx.x;
    int wave = tid >> 6, lane = tid & 63;
    int wr = wave >> 1, wc = wave & 1;
    int quad = lane >> 4, l15 = lane & 15;
    int rowbase = rb * 128, colbase = cb * 128;
    __shared__ unsigned short lA[128 * 64];
    __shared__ unsigned short lB[128 * 64];
    __shared__ float rred[2][128];
    __shared__ float cred[2][128];
    f32x4 zero = {0.f, 0.f, 0.f, 0.f};
    f32x4 acc[4][4];
#pragma unroll
    for (int r = 0; r < 4; ++r)
#pragma unroll
        for (int c = 0; c < 4; ++c) acc[r][c] = zero;
    const int kIters = D >> 6;
    for (int kt = 0; kt < kIters; ++kt) {
        int k0 = kt << 6;
#pragma unroll
        for (int q = 0; q < 4; ++q) {
            int ch = q * 256 + tid;
            int row = ch >> 3, lc = ch & 7;
            int pc = lc ^ (row & 7);
            const float4* sa = (const float4*)(embF + (size_t)(rowbase + row) * D + k0 + lc * 8);
            const float4* sb = (const float4*)(embF + (size_t)(colbase + row) * D + k0 + lc * 8);
            float4 a0 = sa[0], a1 = sa[1];
            float4 b0 = sb[0], b1 = sb[1];
            u16x8 va = {f2bf(a0.x), f2bf(a0.y), f2bf(a0.z), f2bf(a0.w),
                        f2bf(a1.x), f2bf(a1.y), f2bf(a1.z), f2bf(a1.w)};
            u16x8 vb = {f2bf(b0.x), f2bf(b0.y), f2bf(b0.z), f2bf(b0.w),
                        f2bf(b1.x), f2bf(b1.y), f2bf(b1.z), f2bf(b1.w)};
            *(u16x8*)&lA[(row << 6) + (pc << 3)] = va;
            *(u16x8*)&lB[(row << 6) + (pc << 3)] = vb;
        }
        __syncthreads();
#pragma unroll
        for (int h = 0; h < 2; ++h) {
            bf16x8 af[4], bfr[4];
#pragma unroll
            for (int r = 0; r < 4; ++r) {
                int row = wr * 64 + r * 16 + l15;
                int pc = (h * 4 + quad) ^ (l15 & 7);
                af[r] = *(const bf16x8*)&lA[(row << 6) + (pc << 3)];
            }
#pragma unroll
            for (int c = 0; c < 4; ++c) {
                int row = wc * 64 + c * 16 + l15;
                int pc = (h * 4 + quad) ^ (l15 & 7);
                bfr[c] = *(const bf16x8*)&lB[(row << 6) + (pc << 3)];
            }
#pragma unroll
            for (int r = 0; r < 4; ++r)
#pragma unroll
                for (int c = 0; c < 4; ++c)
                    acc[r][c] = __builtin_amdgcn_mfma_f32_16x16x32_bf16(af[r], bfr[c], acc[r][c], 0, 0, 0);
        }
        __syncthreads();
    }
    float rs[4][4], cs[4];
#pragma unroll
    for (int r = 0; r < 4; ++r)
#pragma unroll
        for (int v = 0; v < 4; ++v) rs[r][v] = 0.f;
#pragma unroll
    for (int c = 0; c < 4; ++c) cs[c] = 0.f;
#pragma unroll
    for (int r = 0; r < 4; ++r)
#pragma unroll
        for (int c = 0; c < 4; ++c) {
            f32x4 a = acc[r][c];
            int gcol = colbase + wc * 64 + c * 16 + l15;
#pragma unroll
            for (int v = 0; v < 4; ++v) {
                int grow = rowbase + wr * 64 + r * 16 + quad * 4 + v;
                float e = (grow < gcol) ? __expf((a[v] - 1.0f) * INV_T) : 0.f;
                rs[r][v] += e;
                cs[c] += e;
            }
        }
#pragma unroll
    for (int m = 1; m <= 8; m <<= 1)
#pragma unroll
        for (int r = 0; r < 4; ++r)
#pragma unroll
            for (int v = 0; v < 4; ++v) rs[r][v] += __shfl_xor(rs[r][v], m, 64);
    if (l15 == 0)
#pragma unroll
        for (int r = 0; r < 4; ++r)
#pragma unroll
            for (int v = 0; v < 4; ++v)
                rred[wc][wr * 64 + r * 16 + quad * 4 + v] = rs[r][v];
#pragma unroll
    for (int m = 16; m <= 32; m <<= 1)
#pragma unroll
        for (int c = 0; c < 4; ++c) cs[c] += __shfl_xor(cs[c], m, 64);
    if (quad == 0)
#pragma unroll
        for (int c = 0; c < 4; ++c) cred[wr][wc * 64 + c * 16 + l15] = cs[c];
    __syncthreads();
    if (tid < 128) {
        atomicAdd(&sumexp[rowbase + tid], rred[0][tid] + rred[1][tid]);
    } else {
        int u = tid & 127;
        atomicAdd(&sumexp[colbase + u], cred[0][u] + cred[1][u]);
    }
}

// ---- finalize, emb-free + fast s_mp reduction + folded combine ----
// r8's regression fixed: 4-accumulator ILP, 64 loads/thread (was 128 serial),
// all 32 blocks participate (32 dims each), nPart=512.
__global__ void __launch_bounds__(256) k_fin(const float* __restrict__ Sp,
                                             const float* __restrict__ sumexp,
                                             const int* __restrict__ labels,
                                             const float* __restrict__ outv,
                                             const float* __restrict__ s_mp,
                                             const float* __restrict__ center,
                                             const float* __restrict__ rmp,
                                             const float* __restrict__ rhp,
                                             float* __restrict__ scal,
                                             unsigned* __restrict__ done_ctr,
                                             float* __restrict__ out,
                                             int D, int B, int nPart) {
    int t = threadIdx.x, lane = t & 63, wave = t >> 6;
    int i = blockIdx.x * blockDim.x + t;
    float rm = rmp[0], rh = rhp[0];
    float a[9];
#pragma unroll
    for (int k = 0; k < 9; ++k) a[k] = 0.f;
    if (i < B) {
        float LP = Sp[i];
        float eS = __expf(LP - INV_T);
        float lse = INV_T + __logf(sumexp[i] + eS);
        float d = outv[5 + i];
        bool mach = (labels[i] == 0);
        a[2] = eS;
        if (mach) {
            a[4] = lse; a[3] = LP; a[5] = d * d; a[8] = 1.f;
            float x = d - rm; a[0] = (x > 0.f) ? x * x : 0.f;
        } else {
            float x = rh - d; a[1] = (x > 0.f) ? x * x : 0.f;
        }
    }
    if (blockIdx.x == 0)
        for (int j = t; j < D; j += blockDim.x) { float cv = center[j]; a[7] += cv * cv; }
    // s_mp reduce: 32 dims/block, 8 partial-groups, 4-acc ILP (nPart%32==0)
    __shared__ float sacc[8][33];
    int pg = t >> 5, dl = t & 31;
    for (int dbase = blockIdx.x * 32; dbase < D; dbase += gridDim.x * 32) {
        int d = dbase + dl;
        float a0 = 0.f, a1 = 0.f, a2 = 0.f, a3 = 0.f;
        if (d < D) {
            for (int p = pg; p < nPart; p += 32) {
                a0 += s_mp[(size_t)p * D + d];
                a1 += s_mp[(size_t)(p + 8) * D + d];
                a2 += s_mp[(size_t)(p + 16) * D + d];
                a3 += s_mp[(size_t)(p + 24) * D + d];
            }
        }
        sacc[pg][dl] = (a0 + a1) + (a2 + a3);
        __syncthreads();
        if (t < 32 && dbase + t < D) {
            float s = sacc[0][t] + sacc[1][t] + sacc[2][t] + sacc[3][t] +
                      sacc[4][t] + sacc[5][t] + sacc[6][t] + sacc[7][t];
            a[6] += s * s;
        }
        __syncthreads();
    }
#pragma unroll
    for (int m = 1; m <= 32; m <<= 1)
#pragma unroll
        for (int k = 0; k < 9; ++k) a[k] += __shfl_xor(a[k], m, 64);
    __shared__ float red[4][9];
    if (lane == 0)
#pragma unroll
        for (int k = 0; k < 9; ++k) red[wave][k] = a[k];
    __syncthreads();
    if (t < 9) {
        float v = red[0][t] + red[1][t] + red[2][t] + red[3][t];
        atomicAdd(&scal[t], v);
    }
    __syncthreads();
    if (t == 0) {
        __threadfence();
        unsigned done = atomicAdd(done_ctr, 1u);
        if (done == (unsigned)gridDim.x - 1) {
            __threadfence();
            float s[9];
#pragma unroll
            for (int k = 0; k < 9; ++k) s[k] = atomicAdd(&scal[k], 0.f);
            int nm = (int)(s[8] + 0.5f);
            int nh = B - nm;
            float nmf = (float)(nm > 1 ? nm : 1);
            float nhf = (float)(nh > 1 ? nh : 1);
            float loss_m = s[0] / nmf;
            float loss_h = s[1] / nhf;
            float loss_shell = loss_m + loss_h;
            float lse_p = INV_T + __logf(s[2]);
            float proto = lse_p - s[3] / nmf;
            // sum_m sd = sum_m d^2 + (2/INV_T) * sum_m LP - nm * ||c||^2
            float sum_sd = s[5] + 2.f * s[3] / INV_T - (float)nm * s[7];
            float pos_m = INV_T * (s[6] - sum_sd) + s[3];
            float con = s[4] - pos_m / nmf;
            int denom = (nm + 1 > 1) ? nm + 1 : 1;
            float lc = (con + proto) / (float)denom;
            if (!(nm > 0 && nh > 0)) lc = 0.f;
            out[0] = loss_shell + lc;
            out[1] = loss_shell;
            out[2] = loss_m;
            out[3] = loss_h;
            out[4] = lc;
        }
    }
}

extern "C" void kernel_launch(void* const* d_in, const int* in_sizes, int n_in,
                              void* d_out, int out_size, void* d_ws, size_t ws_size,
                              hipStream_t stream) {
    const float* emb = (const float*)d_in[0];
    const float* center = (const float*)d_in[1];
    const float* rmp = (const float*)d_in[2];
    const float* rhp = (const float*)d_in[3];
    const int* labels = (const int*)d_in[4];
    float* out = (float*)d_out;
    const int B = in_sizes[4];
    const int D = in_sizes[1];

    const int nPart = B / 16;            // k_geom blocks = partial slices
    size_t qBytes = (size_t)B * D;       // fp8 copy
    size_t partBytes = (size_t)nPart * D * 4;
    size_t auxBytes = (size_t)B * 4 + 64 + (size_t)B * 4 + partBytes;
    bool pre = (ws_size >= qBytes + auxBytes) && (B % 256 == 0) &&
               (D % 256 == 0) && (D <= 1024);
    size_t Z0 = pre ? qBytes : 0;

    char* ws = (char*)d_ws;
    unsigned char* embQ = (unsigned char*)ws;
    float* sumexp = (float*)(ws + Z0);                        // B*4
    float* scal = (float*)(ws + Z0 + (size_t)B * 4);          // 64B
    unsigned* done_ctr = (unsigned*)(scal + 12);
    float* Sp = (float*)(ws + Z0 + (size_t)B * 4 + 64);       // B*4 (fully written)
    float* s_mp = (float*)(ws + Z0 + (size_t)B * 4 + 64 + (size_t)B * 4);

    if (pre) {
        // k_quant zeroes sumexp/scal/done_ctr (no memset dispatch)
        k_quant<<<B / 8, D / 4, 0, stream>>>(emb, embQ, sumexp, scal, done_ctr, D);
    } else {
        hipMemsetAsync(ws + Z0, 0, (size_t)B * 4 + 64, stream);
    }

    k_geom<<<B / 16, D / 4, 0, stream>>>(emb, center, labels, out, Sp, s_mp, D);

    int nT = B / 128;
    int nBlocks = nT * (nT + 1) / 2;
    if (pre) k_sumexp_mx<<<nBlocks, 256, 0, stream>>>(embQ, sumexp, D, nT);
    else     k_sumexp_fb<<<nBlocks, 256, 0, stream>>>(emb, sumexp, D, nT);

    k_fin<<<(B + 255) / 256, 256, 0, stream>>>(Sp, sumexp, labels, out, s_mp,
                                               center, rmp, rhp, scal,
                                               done_ctr, out, D, B, nPart);
}

// Round 11
// 171.248 us; speedup vs baseline: 1.1446x; 1.0081x over previous
//
#include <hip/hip_runtime.h>

#define INV_T 14.285714285714286f  // 1/0.07
#define C1 0.055803571428571425f   // INV_T / 256 (undoes the 16x-per-input fp8 scale)

typedef float f32x16 __attribute__((ext_vector_type(16)));
typedef float f32x4 __attribute__((ext_vector_type(4)));
typedef int i32x4v __attribute__((ext_vector_type(4)));
typedef int i32x8 __attribute__((ext_vector_type(8)));

__device__ __forceinline__ unsigned char f2e4m3(float f) {
    unsigned char s = (unsigned char)((__float_as_uint(f) >> 24) & 0x80);
    float a = fabsf(f);
    if (a > 448.f) a = 448.f;
    if (a == 0.f) return s;
    int e = (int)((__float_as_uint(a) >> 23) & 0xFF) - 127;
    if (e < -10) return s;
    if (e < -6) e = -6;
    float scale = __int_as_float((unsigned)(130 - e) << 23);  // 2^(3-e)
    int mi = (int)rintf(a * scale);
    if (mi >= 16) { mi >>= 1; ++e; }
    if (mi < 8) return s | (unsigned char)mi;                  // subnormal (e==-6)
    return s | (unsigned char)(((e + 7) << 3) | (mi - 8));
}

__device__ __forceinline__ void async16(void* l, const void* g) {
    __builtin_amdgcn_global_load_lds(
        (const __attribute__((address_space(1))) unsigned int*)g,
        (__attribute__((address_space(3))) unsigned int*)l, 16, 0, 0);
}

// ---- Phase B first: geometry (distance/Sp) + machine column partials ----
// Runs FIRST: streams emb (33.5MB) -> warms L3 for k_quant's re-read.
__global__ void __launch_bounds__(256) k_geom(const float* __restrict__ emb,
                                              const float* __restrict__ center,
                                              const int* __restrict__ labels,
                                              float* __restrict__ out,
                                              float* __restrict__ Sp,
                                              float* __restrict__ s_mp,
                                              int D) {
    int t = threadIdx.x;                 // blockDim = D/4
    int wave = t >> 6, lane = t & 63;
    int nw = blockDim.x >> 6;
    int r0 = blockIdx.x * 16;
    float4 c = ((const float4*)center)[t];
    float d2p[16], spp[16];
    float4 colacc = {0.f, 0.f, 0.f, 0.f};
#pragma unroll
    for (int g = 0; g < 2; ++g) {
        int rbase = r0 + g * 8;
        float4 e[8];
#pragma unroll
        for (int r = 0; r < 8; ++r)
            e[r] = ((const float4*)(emb + (size_t)(rbase + r) * D))[t];
        int lab[8];
#pragma unroll
        for (int r = 0; r < 8; ++r) lab[r] = labels[rbase + r];
#pragma unroll
        for (int r = 0; r < 8; ++r) {
            float sc = (lab[r] == 0) ? 1.f : 0.f;
            float dx = e[r].x - c.x, dy = e[r].y - c.y,
                  dz = e[r].z - c.z, dw = e[r].w - c.w;
            d2p[g * 8 + r] = dx * dx + dy * dy + dz * dz + dw * dw;
            spp[g * 8 + r] = e[r].x * c.x + e[r].y * c.y + e[r].z * c.z + e[r].w * c.w;
            colacc.x += e[r].x * sc; colacc.y += e[r].y * sc;
            colacc.z += e[r].z * sc; colacc.w += e[r].w * sc;
        }
    }
    // deferred interleaved shuffle reduces (32 independent chains)
#pragma unroll
    for (int m = 1; m <= 32; m <<= 1)
#pragma unroll
        for (int r = 0; r < 16; ++r) {
            d2p[r] += __shfl_xor(d2p[r], m, 64);
            spp[r] += __shfl_xor(spp[r], m, 64);
        }
    __shared__ float redD[16][4];
    __shared__ float redS[16][4];
    if (lane == 0)
#pragma unroll
        for (int r = 0; r < 16; ++r) { redD[r][wave] = d2p[r]; redS[r][wave] = spp[r]; }

    ((float4*)(s_mp + (size_t)blockIdx.x * D))[t] = colacc;  // slice, no atomics

    __syncthreads();
    if (t < 16) {
        float d2 = 0.f, sp = 0.f;
        for (int w = 0; w < nw; ++w) { d2 += redD[t][w]; sp += redS[t][w]; }
        out[5 + r0 + t] = sqrtf(d2);
        Sp[r0 + t] = sp * INV_T;
    }
}

// ---- Phase A second: fp8 recode (emb L3-warm; embQ lands hot for sumexp) ----
__global__ void __launch_bounds__(256) k_quant(const float* __restrict__ emb,
                                               unsigned char* __restrict__ embQ,
                                               float* __restrict__ sumexp,
                                               float* __restrict__ scal,
                                               unsigned* __restrict__ done_ctr,
                                               int D) {
    int t = threadIdx.x;                 // blockDim = D/4
    int r0 = blockIdx.x * 8;
    if (t < 8) sumexp[blockIdx.x * 8 + t] = 0.f;
    if (blockIdx.x == 0) {
        if (t < 12) scal[t] = 0.f;
        if (t == 12) *done_ctr = 0u;
    }
    float4 e[8];
#pragma unroll
    for (int r = 0; r < 8; ++r)
        e[r] = ((const float4*)(emb + (size_t)(r0 + r) * D))[t];
#pragma unroll
    for (int r = 0; r < 8; ++r) {
#if __has_builtin(__builtin_amdgcn_cvt_pk_fp8_f32)
        int p = 0;
        p = __builtin_amdgcn_cvt_pk_fp8_f32(e[r].x * 16.f, e[r].y * 16.f, p, false);
        p = __builtin_amdgcn_cvt_pk_fp8_f32(e[r].z * 16.f, e[r].w * 16.f, p, true);
        ((int*)(embQ + (size_t)(r0 + r) * D))[t] = p;
#else
        ((uchar4*)(embQ + (size_t)(r0 + r) * D))[t] =
            make_uchar4(f2e4m3(e[r].x * 16.f), f2e4m3(e[r].y * 16.f),
                        f2e4m3(e[r].z * 16.f), f2e4m3(e[r].w * 16.f));
#endif
    }
}

// ---- sumexp via MX fp8 MFMA (round-0 best structure; swizzle removed:
// r0 no-swizzle 71.7-71.8 vs r4-r8 swizzled 72.4-73.2 — consistent ~1% cost,
// matches guide m160 "swizzle costs ~2% when L3-fit") ----
#define MXMFMA(a, b, c) __builtin_amdgcn_mfma_scale_f32_32x32x64_f8f6f4( \
    (a), (b), (c), 0, 0, 0, 0x7F7F7F7F, 0, 0x7F7F7F7F)

__global__ void __launch_bounds__(256, 2)
k_sumexp_mx(const unsigned char* __restrict__ embQ, float* __restrict__ sumexp,
            int D, int nT) {
    const int n = nT;
    int bid = blockIdx.x;
    float nf = (float)n + 0.5f;
    int rb = (int)(nf - sqrtf(fmaxf(nf * nf - 2.0f * (float)bid, 0.f)));
    if (rb < 0) rb = 0;
    if (rb > n - 1) rb = n - 1;
#define TRI_OFF(r) ((r) * n - ((r) * ((r)-1)) / 2)
    while (rb + 1 <= n - 1 && TRI_OFF(rb + 1) <= bid) ++rb;
    while (rb > 0 && TRI_OFF(rb) > bid) --rb;
    int cb = rb + (bid - TRI_OFF(rb));
#undef TRI_OFF
    int rowbase = rb * 128, colbase = cb * 128;

    int tid = threadIdx.x;
    int wave = tid >> 6, lane = tid & 63;
    int wr = wave >> 1, wc = wave & 1;
    int l31 = lane & 31, kk = lane >> 5;

    __shared__ unsigned char sA[2][16384];
    __shared__ unsigned char sB[2][16384];
    __shared__ float rred[2][128];
    __shared__ float cred[2][128];

    f32x16 acc[2][2];
#pragma unroll
    for (int fr = 0; fr < 2; ++fr)
#pragma unroll
        for (int fc = 0; fc < 2; ++fc)
#pragma unroll
            for (int v = 0; v < 16; ++v) acc[fr][fc][v] = 0.f;

    const int kG = D >> 7;

    const unsigned char* gSA[4];
    const unsigned char* gSB[4];
    unsigned int dstOff[4];
#pragma unroll
    for (int q = 0; q < 4; ++q) {
        int ch = q * 256 + tid;
        int row = ch >> 3, lc = ch & 7;
        int gc = lc ^ (row & 7);
        gSA[q] = embQ + (size_t)(rowbase + row) * D + gc * 16;
        gSB[q] = embQ + (size_t)(colbase + row) * D + gc * 16;
        dstOff[q] = (unsigned)ch << 4;
    }

    auto stage = [&](int buf, int kt) {
        int ko = kt << 7;
#pragma unroll
        for (int q = 0; q < 4; ++q) {
            async16(&sA[buf][dstOff[q]], gSA[q] + ko);
            async16(&sB[buf][dstOff[q]], gSB[q] + ko);
        }
    };

    int e7 = (l31 & 7) << 4;
    int offs[2][2];
#pragma unroll
    for (int h = 0; h < 2; ++h)
#pragma unroll
        for (int j = 0; j < 2; ++j)
            offs[h][j] = (((h * 4 + kk * 2 + j) << 4) ^ e7);
    int aBase0 = (wr * 64 + l31) << 7;
    int aBase1 = aBase0 + (32 << 7);
    int bBase0 = (wc * 64 + l31) << 7;
    int bBase1 = bBase0 + (32 << 7);

    stage(0, 0);
    for (int kt = 0; kt < kG; ++kt) {
        int cur = kt & 1;
        __syncthreads();
        if (kt + 1 < kG) stage(cur ^ 1, kt + 1);
        const unsigned char* A = sA[cur];
        const unsigned char* Bp = sB[cur];
#pragma unroll
        for (int h = 0; h < 2; ++h) {
            i32x8 av[2], bv[2];
            {
                i32x4v lo = *(const i32x4v*)&A[aBase0 + offs[h][0]];
                i32x4v hi = *(const i32x4v*)&A[aBase0 + offs[h][1]];
                av[0] = __builtin_shufflevector(lo, hi, 0, 1, 2, 3, 4, 5, 6, 7);
            }
            {
                i32x4v lo = *(const i32x4v*)&A[aBase1 + offs[h][0]];
                i32x4v hi = *(const i32x4v*)&A[aBase1 + offs[h][1]];
                av[1] = __builtin_shufflevector(lo, hi, 0, 1, 2, 3, 4, 5, 6, 7);
            }
            {
                i32x4v lo = *(const i32x4v*)&Bp[bBase0 + offs[h][0]];
                i32x4v hi = *(const i32x4v*)&Bp[bBase0 + offs[h][1]];
                bv[0] = __builtin_shufflevector(lo, hi, 0, 1, 2, 3, 4, 5, 6, 7);
            }
            {
                i32x4v lo = *(const i32x4v*)&Bp[bBase1 + offs[h][0]];
                i32x4v hi = *(const i32x4v*)&Bp[bBase1 + offs[h][1]];
                bv[1] = __builtin_shufflevector(lo, hi, 0, 1, 2, 3, 4, 5, 6, 7);
            }
#pragma unroll
            for (int fr = 0; fr < 2; ++fr)
#pragma unroll
                for (int fc = 0; fc < 2; ++fc)
                    acc[fr][fc] = MXMFMA(av[fr], bv[fc], acc[fr][fc]);
        }
    }

    float rs[2][16];
    float cs[2] = {0.f, 0.f};
#pragma unroll
    for (int fr = 0; fr < 2; ++fr)
#pragma unroll
        for (int v = 0; v < 16; ++v) rs[fr][v] = 0.f;

#pragma unroll
    for (int fr = 0; fr < 2; ++fr)
#pragma unroll
        for (int fc = 0; fc < 2; ++fc) {
            int gcol = colbase + wc * 64 + fc * 32 + l31;
#pragma unroll
            for (int v = 0; v < 16; ++v) {
                int grow = rowbase + wr * 64 + fr * 32 + (v & 3) + 8 * (v >> 2) + 4 * kk;
                float e = (grow < gcol) ? __expf(acc[fr][fc][v] * C1 - INV_T) : 0.f;
                rs[fr][v] += e;
                cs[fc] += e;
            }
        }

#pragma unroll
    for (int m = 1; m <= 16; m <<= 1)
#pragma unroll
        for (int fr = 0; fr < 2; ++fr)
#pragma unroll
            for (int v = 0; v < 16; ++v) rs[fr][v] += __shfl_xor(rs[fr][v], m, 64);
    if (l31 == 0)
#pragma unroll
        for (int fr = 0; fr < 2; ++fr)
#pragma unroll
            for (int v = 0; v < 16; ++v)
                rred[wc][wr * 64 + fr * 32 + (v & 3) + 8 * (v >> 2) + 4 * kk] = rs[fr][v];

#pragma unroll
    for (int fc = 0; fc < 2; ++fc) cs[fc] += __shfl_xor(cs[fc], 32, 64);
    if (kk == 0)
#pragma unroll
        for (int fc = 0; fc < 2; ++fc) cred[wr][wc * 64 + fc * 32 + l31] = cs[fc];

    __syncthreads();
    if (tid < 128) {
        atomicAdd(&sumexp[rowbase + tid], rred[0][tid] + rred[1][tid]);
    } else {
        int u = tid - 128;
        atomicAdd(&sumexp[colbase + u], cred[0][u] + cred[1][u]);
    }
}

// ---- fallback (no workspace): bf16-via-LDS, fp32 inline convert ----
typedef __bf16 bf16x8 __attribute__((ext_vector_type(8)));
typedef unsigned short u16x8 __attribute__((ext_vector_type(8)));
__device__ __forceinline__ unsigned short f2bf(float f) {
    unsigned int x = __float_as_uint(f);
    x += 0x7fffu + ((x >> 16) & 1u);
    return (unsigned short)(x >> 16);
}
__global__ void __launch_bounds__(256) k_sumexp_fb(const float* __restrict__ embF,
                                                   float* __restrict__ sumexp, int D, int nTiles) {
    int bid = blockIdx.x;
    const int n = nTiles;
    float nf = (float)n + 0.5f;
    int rb = (int)(nf - sqrtf(fmaxf(nf * nf - 2.0f * (float)bid, 0.f)));
    if (rb < 0) rb = 0;
    if (rb > n - 1) rb = n - 1;
#define TRI_OFF(r) ((r) * n - ((r) * ((r)-1)) / 2)
    while (rb + 1 <= n - 1 && TRI_OFF(rb + 1) <= bid) ++rb;
    while (rb > 0 && TRI_OFF(rb) > bid) --rb;
    int cb = rb + (bid - TRI_OFF(rb));
#undef TRI_OFF
    int tid = threadIdx.x;
    int wave = tid >> 6, lane = tid & 63;
    int wr = wave >> 1, wc = wave & 1;
    int quad = lane >> 4, l15 = lane & 15;
    int rowbase = rb * 128, colbase = cb * 128;
    __shared__ unsigned short lA[128 * 64];
    __shared__ unsigned short lB[128 * 64];
    __shared__ float rred[2][128];
    __shared__ float cred[2][128];
    f32x4 zero = {0.f, 0.f, 0.f, 0.f};
    f32x4 acc[4][4];
#pragma unroll
    for (int r = 0; r < 4; ++r)
#pragma unroll
        for (int c = 0; c < 4; ++c) acc[r][c] = zero;
    const int kIters = D >> 6;
    for (int kt = 0; kt < kIters; ++kt) {
        int k0 = kt << 6;
#pragma unroll
        for (int q = 0; q < 4; ++q) {
            int ch = q * 256 + tid;
            int row = ch >> 3, lc = ch & 7;
            int pc = lc ^ (row & 7);
            const float4* sa = (const float4*)(embF + (size_t)(rowbase + row) * D + k0 + lc * 8);
            const float4* sb = (const float4*)(embF + (size_t)(colbase + row) * D + k0 + lc * 8);
            float4 a0 = sa[0], a1 = sa[1];
            float4 b0 = sb[0], b1 = sb[1];
            u16x8 va = {f2bf(a0.x), f2bf(a0.y), f2bf(a0.z), f2bf(a0.w),
                        f2bf(a1.x), f2bf(a1.y), f2bf(a1.z), f2bf(a1.w)};
            u16x8 vb = {f2bf(b0.x), f2bf(b0.y), f2bf(b0.z), f2bf(b0.w),
                        f2bf(b1.x), f2bf(b1.y), f2bf(b1.z), f2bf(b1.w)};
            *(u16x8*)&lA[(row << 6) + (pc << 3)] = va;
            *(u16x8*)&lB[(row << 6) + (pc << 3)] = vb;
        }
        __syncthreads();
#pragma unroll
        for (int h = 0; h < 2; ++h) {
            bf16x8 af[4], bfr[4];
#pragma unroll
            for (int r = 0; r < 4; ++r) {
                int row = wr * 64 + r * 16 + l15;
                int pc = (h * 4 + quad) ^ (l15 & 7);
                af[r] = *(const bf16x8*)&lA[(row << 6) + (pc << 3)];
            }
#pragma unroll
            for (int c = 0; c < 4; ++c) {
                int row = wc * 64 + c * 16 + l15;
                int pc = (h * 4 + quad) ^ (l15 & 7);
                bfr[c] = *(const bf16x8*)&lB[(row << 6) + (pc << 3)];
            }
#pragma unroll
            for (int r = 0; r < 4; ++r)
#pragma unroll
                for (int c = 0; c < 4; ++c)
                    acc[r][c] = __builtin_amdgcn_mfma_f32_16x16x32_bf16(af[r], bfr[c], acc[r][c], 0, 0, 0);
        }
        __syncthreads();
    }
    float rs[4][4], cs[4];
#pragma unroll
    for (int r = 0; r < 4; ++r)
#pragma unroll
        for (int v = 0; v < 4; ++v) rs[r][v] = 0.f;
#pragma unroll
    for (int c = 0; c < 4; ++c) cs[c] = 0.f;
#pragma unroll
    for (int r = 0; r < 4; ++r)
#pragma unroll
        for (int c = 0; c < 4; ++c) {
            f32x4 a = acc[r][c];
            int gcol = colbase + wc * 64 + c * 16 + l15;
#pragma unroll
            for (int v = 0; v < 4; ++v) {
                int grow = rowbase + wr * 64 + r * 16 + quad * 4 + v;
                float e = (grow < gcol) ? __expf((a[v] - 1.0f) * INV_T) : 0.f;
                rs[r][v] += e;
                cs[c] += e;
            }
        }
#pragma unroll
    for (int m = 1; m <= 8; m <<= 1)
#pragma unroll
        for (int r = 0; r < 4; ++r)
#pragma unroll
            for (int v = 0; v < 4; ++v) rs[r][v] += __shfl_xor(rs[r][v], m, 64);
    if (l15 == 0)
#pragma unroll
        for (int r = 0; r < 4; ++r)
#pragma unroll
            for (int v = 0; v < 4; ++v)
                rred[wc][wr * 64 + r * 16 + quad * 4 + v] = rs[r][v];
#pragma unroll
    for (int m = 16; m <= 32; m <<= 1)
#pragma unroll
        for (int c = 0; c < 4; ++c) cs[c] += __shfl_xor(cs[c], m, 64);
    if (quad == 0)
#pragma unroll
        for (int c = 0; c < 4; ++c) cred[wr][wc * 64 + c * 16 + l15] = cs[c];
    __syncthreads();
    if (tid < 128) {
        atomicAdd(&sumexp[rowbase + tid], rred[0][tid] + rred[1][tid]);
    } else {
        int u = tid & 127;
        atomicAdd(&sumexp[colbase + u], cred[0][u] + cred[1][u]);
    }
}

// ---- finalize, emb-free + fast s_mp reduction + folded combine ----
__global__ void __launch_bounds__(256) k_fin(const float* __restrict__ Sp,
                                             const float* __restrict__ sumexp,
                                             const int* __restrict__ labels,
                                             const float* __restrict__ outv,
                                             const float* __restrict__ s_mp,
                                             const float* __restrict__ center,
                                             const float* __restrict__ rmp,
                                             const float* __restrict__ rhp,
                                             float* __restrict__ scal,
                                             unsigned* __restrict__ done_ctr,
                                             float* __restrict__ out,
                                             int D, int B, int nPart) {
    int t = threadIdx.x, lane = t & 63, wave = t >> 6;
    int i = blockIdx.x * blockDim.x + t;
    float rm = rmp[0], rh = rhp[0];
    float a[9];
#pragma unroll
    for (int k = 0; k < 9; ++k) a[k] = 0.f;
    if (i < B) {
        float LP = Sp[i];
        float eS = __expf(LP - INV_T);
        float lse = INV_T + __logf(sumexp[i] + eS);
        float d = outv[5 + i];
        bool mach = (labels[i] == 0);
        a[2] = eS;
        if (mach) {
            a[4] = lse; a[3] = LP; a[5] = d * d; a[8] = 1.f;
            float x = d - rm; a[0] = (x > 0.f) ? x * x : 0.f;
        } else {
            float x = rh - d; a[1] = (x > 0.f) ? x * x : 0.f;
        }
    }
    if (blockIdx.x == 0)
        for (int j = t; j < D; j += blockDim.x) { float cv = center[j]; a[7] += cv * cv; }
    // s_mp reduce: 32 dims/block, 8 partial-groups, 4-acc ILP (nPart%32==0)
    __shared__ float sacc[8][33];
    int pg = t >> 5, dl = t & 31;
    for (int dbase = blockIdx.x * 32; dbase < D; dbase += gridDim.x * 32) {
        int d = dbase + dl;
        float a0 = 0.f, a1 = 0.f, a2 = 0.f, a3 = 0.f;
        if (d < D) {
            for (int p = pg; p < nPart; p += 32) {
                a0 += s_mp[(size_t)p * D + d];
                a1 += s_mp[(size_t)(p + 8) * D + d];
                a2 += s_mp[(size_t)(p + 16) * D + d];
                a3 += s_mp[(size_t)(p + 24) * D + d];
            }
        }
        sacc[pg][dl] = (a0 + a1) + (a2 + a3);
        __syncthreads();
        if (t < 32 && dbase + t < D) {
            float s = sacc[0][t] + sacc[1][t] + sacc[2][t] + sacc[3][t] +
                      sacc[4][t] + sacc[5][t] + sacc[6][t] + sacc[7][t];
            a[6] += s * s;
        }
        __syncthreads();
    }
#pragma unroll
    for (int m = 1; m <= 32; m <<= 1)
#pragma unroll
        for (int k = 0; k < 9; ++k) a[k] += __shfl_xor(a[k], m, 64);
    __shared__ float red[4][9];
    if (lane == 0)
#pragma unroll
        for (int k = 0; k < 9; ++k) red[wave][k] = a[k];
    __syncthreads();
    if (t < 9) {
        float v = red[0][t] + red[1][t] + red[2][t] + red[3][t];
        atomicAdd(&scal[t], v);
    }
    __syncthreads();
    if (t == 0) {
        __threadfence();
        unsigned done = atomicAdd(done_ctr, 1u);
        if (done == (unsigned)gridDim.x - 1) {
            __threadfence();
            float s[9];
#pragma unroll
            for (int k = 0; k < 9; ++k) s[k] = atomicAdd(&scal[k], 0.f);
            int nm = (int)(s[8] + 0.5f);
            int nh = B - nm;
            float nmf = (float)(nm > 1 ? nm : 1);
            float nhf = (float)(nh > 1 ? nh : 1);
            float loss_m = s[0] / nmf;
            float loss_h = s[1] / nhf;
            float loss_shell = loss_m + loss_h;
            float lse_p = INV_T + __logf(s[2]);
            float proto = lse_p - s[3] / nmf;
            // sum_m sd = sum_m d^2 + (2/INV_T) * sum_m LP - nm * ||c||^2
            float sum_sd = s[5] + 2.f * s[3] / INV_T - (float)nm * s[7];
            float pos_m = INV_T * (s[6] - sum_sd) + s[3];
            float con = s[4] - pos_m / nmf;
            int denom = (nm + 1 > 1) ? nm + 1 : 1;
            float lc = (con + proto) / (float)denom;
            if (!(nm > 0 && nh > 0)) lc = 0.f;
            out[0] = loss_shell + lc;
            out[1] = loss_shell;
            out[2] = loss_m;
            out[3] = loss_h;
            out[4] = lc;
        }
    }
}

extern "C" void kernel_launch(void* const* d_in, const int* in_sizes, int n_in,
                              void* d_out, int out_size, void* d_ws, size_t ws_size,
                              hipStream_t stream) {
    const float* emb = (const float*)d_in[0];
    const float* center = (const float*)d_in[1];
    const float* rmp = (const float*)d_in[2];
    const float* rhp = (const float*)d_in[3];
    const int* labels = (const int*)d_in[4];
    float* out = (float*)d_out;
    const int B = in_sizes[4];
    const int D = in_sizes[1];

    const int nPart = B / 16;            // k_geom blocks = partial slices
    size_t qBytes = (size_t)B * D;       // fp8 copy
    size_t partBytes = (size_t)nPart * D * 4;
    size_t auxBytes = (size_t)B * 4 + 64 + (size_t)B * 4 + partBytes;
    bool pre = (ws_size >= qBytes + auxBytes) && (B % 256 == 0) &&
               (D % 256 == 0) && (D <= 1024);
    size_t Z0 = pre ? qBytes : 0;

    char* ws = (char*)d_ws;
    unsigned char* embQ = (unsigned char*)ws;
    float* sumexp = (float*)(ws + Z0);                        // B*4
    float* scal = (float*)(ws + Z0 + (size_t)B * 4);          // 64B
    unsigned* done_ctr = (unsigned*)(scal + 12);
    float* Sp = (float*)(ws + Z0 + (size_t)B * 4 + 64);       // B*4 (fully written)
    float* s_mp = (float*)(ws + Z0 + (size_t)B * 4 + 64 + (size_t)B * 4);

    // Order: geom (warms L3 with emb) -> quant (embQ lands hot) -> sumexp -> fin
    k_geom<<<B / 16, D / 4, 0, stream>>>(emb, center, labels, out, Sp, s_mp, D);

    if (pre) {
        k_quant<<<B / 8, D / 4, 0, stream>>>(emb, embQ, sumexp, scal, done_ctr, D);
    } else {
        hipMemsetAsync(ws + Z0, 0, (size_t)B * 4 + 64, stream);
    }

    int nT = B / 128;
    int nBlocks = nT * (nT + 1) / 2;
    if (pre) k_sumexp_mx<<<nBlocks, 256, 0, stream>>>(embQ, sumexp, D, nT);
    else     k_sumexp_fb<<<nBlocks, 256, 0, stream>>>(emb, sumexp, D, nT);

    k_fin<<<(B + 255) / 256, 256, 0, stream>>>(Sp, sumexp, labels, out, s_mp,
                                               center, rmp, rhp, scal,
                                               done_ctr, out, D, B, nPart);
}